// Round 3
// baseline (211.423 us; speedup 1.0000x reference)
//
#include <hip/hip_runtime.h>
#include <hip/hip_bf16.h>
#include <stdint.h>

#define NN 4096
#define DD 256
#define TH 0.04f

typedef __attribute__((ext_vector_type(4))) float f32x4;
typedef __attribute__((ext_vector_type(8))) short s16x8;

__device__ __forceinline__ unsigned short f2bf(float f) {
  union { float f; uint32_t u; } x; x.f = f;
  uint32_t u = x.u;
  return (unsigned short)((u + 0x7FFFu + ((u >> 16) & 1u)) >> 16);  // RNE
}
__device__ __forceinline__ float bf2f(unsigned short h) {
  union { uint32_t u; float f; } x; x.u = ((uint32_t)h) << 16;
  return x.f;
}

// ---- one pass over A: maskT bf16 [4096v][4096u] + integer degree partials.
// Grid 512 = (32 ut x 16 vt); block tile = [128u][256v]. Thread owns 4 v
// (lane*4) x 32 u (wave*32). Each v-row's 64B output segment is contiguous.
__global__ __launch_bounds__(256) void k_deg(const float* __restrict__ A,
                                             unsigned short* __restrict__ maskT,
                                             unsigned short* __restrict__ rowpartg,  // [16vt][4096u]
                                             unsigned short* __restrict__ colpartg) {// [32ut][4096v]
  __shared__ uint32_t rpl[32][68];            // [u-quad][lane] 4 row-counts/u32, padded
  __shared__ unsigned short clp[4][256];      // [wave][v_loc] col partials
  const int t = threadIdx.x;
  const int l = t & 63, w = t >> 6;
  const int ut = blockIdx.x & 31, vt = blockIdx.x >> 5;
  const int U0 = ut * 128, V0 = vt * 256;
  const int u0 = U0 + w * 32;
  const int vq = l * 4;

  uint32_t out[4][16];                        // [v][u-pair] two bf16 per u32
  uint32_t cs[4] = {0, 0, 0, 0};

#pragma unroll
  for (int g = 0; g < 4; ++g) {
    f32x4 a[8];
#pragma unroll
    for (int s = 0; s < 8; ++s)
      a[s] = *reinterpret_cast<const f32x4*>(A + (size_t)(u0 + g * 8 + s) * NN + V0 + vq);
    uint32_t rp0 = 0, rp1 = 0;
#pragma unroll
    for (int sp = 0; sp < 4; ++sp) {
      uint32_t rc0 = 0, rc1 = 0;
#pragma unroll
      for (int v = 0; v < 4; ++v) {
        uint32_t b0 = (a[2 * sp][v]     >= TH) ? 1u : 0u;
        uint32_t b1 = (a[2 * sp + 1][v] >= TH) ? 1u : 0u;
        out[v][g * 4 + sp] = (b0 ? 0x3F80u : 0u) | (b1 ? 0x3F800000u : 0u);
        cs[v] += b0 + b1;
        rc0 += b0; rc1 += b1;
      }
      rp0 |= rc0 << (16 * sp);   // rows 2sp   -> 16-bit safe? counts<=4, use bytes:
      rp1 |= rc1 << (16 * sp);
    }
    // repack: rp0 holds rows {0,2,4,6} in 4 bytes? above used 16-bit shifts for 4 fields
    // fields: rp0 = rows 2sp at bits 16*sp -> only 2 fields fit; fix: use byte fields.
    // (rewritten below without ambiguity)
    uint32_t q0 = 0, q1 = 0;  // q0: rows g*8+0..3, q1: rows g*8+4..7, byte fields
#pragma unroll
    for (int s = 0; s < 8; ++s) {
      uint32_t rc = 0;
#pragma unroll
      for (int v = 0; v < 4; ++v) rc += (a[s][v] >= TH) ? 1u : 0u;
      if (s < 4) q0 |= rc << (8 * s); else q1 |= rc << (8 * (s - 4));
    }
    rpl[w * 8 + g * 2][l]     = q0;
    rpl[w * 8 + g * 2 + 1][l] = q1;
  }
  // col partials: pack 4 u16
  *reinterpret_cast<uint2*>(&clp[w][vq]) =
      uint2{cs[0] | (cs[1] << 16), cs[2] | (cs[3] << 16)};

  // maskT stores: 64B contiguous per v
#pragma unroll
  for (int v = 0; v < 4; ++v) {
    uint4* dst = reinterpret_cast<uint4*>(maskT + (size_t)(V0 + vq + v) * NN + u0);
#pragma unroll
    for (int c = 0; c < 4; ++c)
      dst[c] = uint4{out[v][4 * c], out[v][4 * c + 1], out[v][4 * c + 2], out[v][4 * c + 3]};
  }
  __syncthreads();
  // reduce row partials: 128 rows, thread t<128 sums byte (t&3) of rpl[t>>2][*]
  if (t < 128) {
    const uint32_t sh = 8 * (t & 3);
    uint32_t s = 0;
#pragma unroll
    for (int c = 0; c < 16; ++c) {
      uint4 x = *reinterpret_cast<const uint4*>(&rpl[t >> 2][c * 4]);
      s += ((x.x >> sh) & 0xFFu) + ((x.y >> sh) & 0xFFu) +
           ((x.z >> sh) & 0xFFu) + ((x.w >> sh) & 0xFFu);
    }
    rowpartg[(size_t)vt * 4096 + U0 + t] = (unsigned short)s;
  }
  // reduce col partials
  uint32_t tot = (uint32_t)clp[0][t] + clp[1][t] + clp[2][t] + clp[3][t];
  colpartg[(size_t)ut * 4096 + V0 + t] = (unsigned short)tot;
}

// ---- fused: degree reduce + rsqrt + W1/W2 transpose->bf16. Grid 48. ------
__global__ __launch_bounds__(256) void k_cnt(const unsigned short* __restrict__ rowpartg,
                                             const unsigned short* __restrict__ colpartg,
                                             const float* __restrict__ W1,
                                             const float* __restrict__ W2,
                                             float* __restrict__ oi,
                                             float* __restrict__ ii,
                                             unsigned short* __restrict__ WTb,
                                             unsigned short* __restrict__ W2Tb) {
  const int t = threadIdx.x;
  const int b = blockIdx.x;
  if (b < 16) {
    const int u = b * 256 + t;
    uint32_t s = 0;
#pragma unroll
    for (int vt = 0; vt < 16; ++vt) s += rowpartg[(size_t)vt * 4096 + u];
    oi[u] = rsqrtf((float)(s + 1u));
  } else if (b < 32) {
    const int v = (b - 16) * 256 + t;
    uint32_t s = 0;
#pragma unroll
    for (int ut = 0; ut < 32; ++ut) s += colpartg[(size_t)ut * 4096 + v];
    ii[v] = rsqrtf((float)(s + 1u));
  } else {
    const int base = (b - 32) * 4096 + t * 16;
#pragma unroll
    for (int e = 0; e < 16; ++e) {
      int idx = base + e;
      int d = idx >> 8, k = idx & 255;
      WTb[idx]  = f2bf(W1[k * 256 + d]);
      W2Tb[idx] = f2bf(W2[k * 256 + d]);
    }
  }
}

// ---- hW = (H * oi[:,None]) @ W  -> hWb [u][d] bf16 and hWbT [d][u] bf16 --
__global__ __launch_bounds__(256) void k_hw(const float* __restrict__ H,
                                            const float* __restrict__ oi,
                                            const unsigned short* __restrict__ WTb,
                                            unsigned short* __restrict__ hWb,
                                            unsigned short* __restrict__ hWbT) {
  __shared__ unsigned short lt[64][260];
  const int t = threadIdx.x;
  const int lane = t & 63, w = t >> 6;
  const int l15 = lane & 15, l4 = lane >> 4;
  const int u0 = blockIdx.x * 64;
  const f32x4 z = {0.f, 0.f, 0.f, 0.f};
  f32x4 acc[4][4];
#pragma unroll
  for (int i = 0; i < 4; ++i)
#pragma unroll
    for (int j = 0; j < 4; ++j) acc[i][j] = z;
  float oiv[4];
#pragma unroll
  for (int i = 0; i < 4; ++i) oiv[i] = oi[u0 + i * 16 + l15];

  for (int ks = 0; ks < 8; ++ks) {
    const int k0 = ks * 32;
    s16x8 af[4];
#pragma unroll
    for (int i = 0; i < 4; ++i) {
      const f32x4* pa = reinterpret_cast<const f32x4*>(H + (size_t)(u0 + i * 16 + l15) * DD + k0 + l4 * 8);
      f32x4 a0 = pa[0], a1 = pa[1];
#pragma unroll
      for (int j = 0; j < 4; ++j) {
        af[i][j]     = (short)f2bf(a0[j] * oiv[i]);
        af[i][j + 4] = (short)f2bf(a1[j] * oiv[i]);
      }
    }
#pragma unroll
    for (int jn = 0; jn < 4; ++jn) {
      const int d = w * 64 + jn * 16 + l15;
      s16x8 bf = *reinterpret_cast<const s16x8*>(WTb + (size_t)d * DD + k0 + l4 * 8);
#pragma unroll
      for (int i = 0; i < 4; ++i)
        acc[i][jn] = __builtin_amdgcn_mfma_f32_16x16x32_bf16(af[i], bf, acc[i][jn], 0, 0, 0);
    }
  }
#pragma unroll
  for (int i = 0; i < 4; ++i)
#pragma unroll
    for (int jn = 0; jn < 4; ++jn) {
      const int d = w * 64 + jn * 16 + l15;
#pragma unroll
      for (int r = 0; r < 4; ++r) {
        const int ul = i * 16 + l4 * 4 + r;
        unsigned short hv = f2bf(acc[i][jn][r]);
        hWb[(size_t)(u0 + ul) * DD + d] = hv;
        lt[ul][d] = hv;
      }
    }
  __syncthreads();
#pragma unroll
  for (int c = 0; c < 8; ++c) {
    uint4 val;
    val.x = (uint32_t)lt[c*8+0][t] | ((uint32_t)lt[c*8+1][t] << 16);
    val.y = (uint32_t)lt[c*8+2][t] | ((uint32_t)lt[c*8+3][t] << 16);
    val.z = (uint32_t)lt[c*8+4][t] | ((uint32_t)lt[c*8+5][t] << 16);
    val.w = (uint32_t)lt[c*8+6][t] | ((uint32_t)lt[c*8+7][t] << 16);
    *reinterpret_cast<uint4*>(hWbT + (size_t)t * NN + u0 + c * 8) = val;
  }
}

// ---- fused SpMM: out[v][d] = relu((sum_u maskT[v][u]*hW[u][d] + hW[v][d])*ii[v] + b[d])
// Grid 256 = (64 v-tiles x 4 d-quarters) XCD-swizzled; block 256 = 4 waves,
// wave = 64v x 16d. Pure loads+MFMA inner loop, depth-1 register prefetch.
__global__ __launch_bounds__(256) void k_spmm(const unsigned short* __restrict__ maskT,
                                              const unsigned short* __restrict__ hWbT,
                                              const unsigned short* __restrict__ hWb,
                                              const float* __restrict__ ii,
                                              const float* __restrict__ bias,
                                              float* __restrict__ out) {
  const int t = threadIdx.x;
  const int lane = t & 63, w = t >> 6;
  const int l15 = lane & 15, l4 = lane >> 4;
  const int lin = blockIdx.x;
  const int xcd = lin & 7, jj = lin >> 3;
  const int vt = xcd * 8 + (jj >> 2), dq = jj & 3;   // 4 d-blocks of a v-tile share an XCD
  const int V0 = vt * 64, D0 = dq * 64;
  const int wd = D0 + w * 16;

  const f32x4 z = {0.f, 0.f, 0.f, 0.f};
  f32x4 acc[4];
#pragma unroll
  for (int i = 0; i < 4; ++i) acc[i] = z;

  const unsigned short* Abase = maskT + (size_t)(V0 + l15) * NN + l4 * 8;
  const unsigned short* Bbase = hWbT + (size_t)(wd + l15) * NN + l4 * 8;

  s16x8 aA[4], aN[4], bB, bN;
#pragma unroll
  for (int i = 0; i < 4; ++i) aA[i] = *reinterpret_cast<const s16x8*>(Abase + (size_t)i * 16 * NN);
  bB = *reinterpret_cast<const s16x8*>(Bbase);

#pragma unroll 1
  for (int kk = 0; kk < 64; ++kk) {
    const int k1 = kk * 64 + 32;
#pragma unroll
    for (int i = 0; i < 4; ++i)
      aN[i] = *reinterpret_cast<const s16x8*>(Abase + (size_t)i * 16 * NN + k1);
    bN = *reinterpret_cast<const s16x8*>(Bbase + k1);
#pragma unroll
    for (int i = 0; i < 4; ++i)
      acc[i] = __builtin_amdgcn_mfma_f32_16x16x32_bf16(aA[i], bB, acc[i], 0, 0, 0);
    const int k2 = (kk * 64 + 64) & 4095;          // wraps to 0 on last iter (unused)
#pragma unroll
    for (int i = 0; i < 4; ++i)
      aA[i] = *reinterpret_cast<const s16x8*>(Abase + (size_t)i * 16 * NN + k2);
    bB = *reinterpret_cast<const s16x8*>(Bbase + k2);
#pragma unroll
    for (int i = 0; i < 4; ++i)
      acc[i] = __builtin_amdgcn_mfma_f32_16x16x32_bf16(aN[i], bN, acc[i], 0, 0, 0);
  }

  const int dcol = wd + l15;
  const float bv = bias[dcol];
#pragma unroll
  for (int i = 0; i < 4; ++i) {
#pragma unroll
    for (int r = 0; r < 4; ++r) {
      const int v = V0 + i * 16 + l4 * 4 + r;
      const float self = bf2f(hWb[(size_t)v * DD + dcol]);
      const float val = (acc[i][r] + self) * ii[v] + bv;
      out[(size_t)v * DD + dcol] = fmaxf(val, 0.f);
    }
  }
}

extern "C" void kernel_launch(void* const* d_in, const int* in_sizes, int n_in,
                              void* d_out, int out_size, void* d_ws, size_t ws_size,
                              hipStream_t stream) {
  const float* A    = (const float*)d_in[0];
  const float* feat = (const float*)d_in[1];
  const float* W1   = (const float*)d_in[2];
  const float* b1   = (const float*)d_in[3];
  const float* W2   = (const float*)d_in[4];
  const float* b2   = (const float*)d_in[5];
  float* out = (float*)d_out;
  char* ws = (char*)d_ws;

  unsigned short* maskT    = (unsigned short*)ws;                          // 32 MiB
  unsigned short* hWbT     = (unsigned short*)(ws + (32u << 20));          // 2 MiB
  unsigned short* hWb      = (unsigned short*)(ws + (34u << 20));          // 2 MiB
  unsigned short* WTb      = (unsigned short*)(ws + (36u << 20));          // 128 KiB
  unsigned short* W2Tb     = (unsigned short*)(ws + (36u << 20) + (1u << 17));
  unsigned short* rowpartg = (unsigned short*)(ws + (36u << 20) + (2u << 17)); // 128 KiB
  unsigned short* colpartg = (unsigned short*)(ws + (36u << 20) + (3u << 17)); // 256 KiB
  float*          oi       = (float*)(ws + (36u << 20) + (5u << 17));
  float*          ii       = oi + NN;

  k_deg<<<512, 256, 0, stream>>>(A, maskT, rowpartg, colpartg);
  k_cnt<<<48, 256, 0, stream>>>(rowpartg, colpartg, W1, W2, oi, ii, WTb, W2Tb);

  // layer 1
  k_hw<<<64, 256, 0, stream>>>(feat, oi, WTb, hWb, hWbT);
  k_spmm<<<256, 256, 0, stream>>>(maskT, hWbT, hWb, ii, b1, out);

  // layer 2
  k_hw<<<64, 256, 0, stream>>>(out, oi, W2Tb, hWb, hWbT);
  k_spmm<<<256, 256, 0, stream>>>(maskT, hWbT, hWb, ii, b2, out + (size_t)NN * DD);
}